// Round 11
// baseline (1193.609 us; speedup 1.0000x reference)
//
#include <hip/hip_runtime.h>
#include <cstdint>
#include <cstddef>

#define LN_ 2
#define HH 8
#define DM 1024
#define FFN_ 4096
#define HDD 128
#define SS 2048
#define BB 2
#define RR (BB*SS)   // 4096 rows

typedef __bf16 bf16x8 __attribute__((ext_vector_type(8)));
typedef __bf16 bf16x4 __attribute__((ext_vector_type(4)));
typedef __bf16 bf16x2 __attribute__((ext_vector_type(2)));
typedef float  f32x4  __attribute__((ext_vector_type(4)));

__device__ __forceinline__ float silu_f(float x) { return x / (1.0f + expf(-x)); }

// async global->LDS, 16B per lane; LDS dest = wave-uniform base + lane*16
__device__ __forceinline__ void glds16(const void* g, void* l) {
  __builtin_amdgcn_global_load_lds(
      (const __attribute__((address_space(1))) unsigned int*)g,
      (__attribute__((address_space(3))) unsigned int*)l, 16, 0, 0);
}

// Packed operand tiles: [128 rows][64 k] bf16 = 16 KiB, within-tile byte =
// row*128 + ((2*k) ^ ((row&7)<<4)). Producers write this; consumers stage it
// linearly via glds16 and read with the same XOR (both-sides, guide §21).

// XCD swizzle (T1): contiguous logical chunk per XCD (bijective, nblk%8==0).
__device__ __forceinline__ int xcd_swz(int lin, int nblk) {
  return (lin & 7) * (nblk >> 3) + (lin >> 3);
}

// ---------------- xPos tables + decay log2-gammas (fp64, matches numpy) -----
__global__ void init_tables_k(float* __restrict__ sq, float* __restrict__ cq,
                              float* __restrict__ sk, float* __restrict__ ck,
                              float* __restrict__ lg2g) {
  int s = blockIdx.x, k = threadIdx.x;
  int j = k >> 1;
  double sv    = (2.0 * j + 0.4 * HDD) / (1.4 * HDD);
  double p     = (double)s / 512.0;
  double scale = pow(sv, p);
  double invf  = pow(10000.0, -((double)j) / 64.0);
  double ang   = (double)s * invf;
  double sn = sin(ang), cs = cos(ang);
  size_t idx = (size_t)s * HDD + k;
  sq[idx] = (float)(sn * scale);
  cq[idx] = (float)(cs * scale);
  sk[idx] = (float)(sn / scale);
  ck[idx] = (float)(cs / scale);
  if (s == 0 && k < HH) {
    double a0 = log(1.0 / 32.0), a1 = log(1.0 / 512.0);
    double x = a0 + (a1 - a0) * ((double)k / 7.0);
    lg2g[k] = (float)(log(1.0 - exp(x)) / log(2.0));
  }
}

// ---------------- LayerNorm -> packed hi/lo swizzled A-operand --------------
__global__ __launch_bounds__(256) void ln_pack_k(
    const float* __restrict__ X, const float* __restrict__ w,
    const float* __restrict__ b, char* __restrict__ ph, char* __restrict__ pl) {
  const int row = blockIdx.x, tid = threadIdx.x;
  const float* x = X + (size_t)row * DM;
  float4 v = *(const float4*)(x + tid * 4);
  float s = v.x + v.y + v.z + v.w;
  float q = v.x * v.x + v.y * v.y + v.z * v.z + v.w * v.w;
#pragma unroll
  for (int o = 32; o > 0; o >>= 1) { s += __shfl_xor(s, o); q += __shfl_xor(q, o); }
  __shared__ float ss[4], qq[4];
  if ((tid & 63) == 0) { ss[tid >> 6] = s; qq[tid >> 6] = q; }
  __syncthreads();
  float S  = ss[0] + ss[1] + ss[2] + ss[3];
  float Qs = qq[0] + qq[1] + qq[2] + qq[3];
  float mu  = S * (1.0f / DM);
  float var = Qs * (1.0f / DM) - mu * mu;
  float rs  = 1.0f / sqrtf(var + 1e-5f);
  float4 wv = *(const float4*)(w + tid * 4);
  float4 bv = *(const float4*)(b + tid * 4);
  float y[4];
  y[0] = (v.x - mu) * rs * wv.x + bv.x;
  y[1] = (v.y - mu) * rs * wv.y + bv.y;
  y[2] = (v.z - mu) * rs * wv.z + bv.z;
  y[3] = (v.w - mu) * rs * wv.w + bv.w;
  bf16x4 hv, lv;
#pragma unroll
  for (int r = 0; r < 4; ++r) {
    __bf16 h = (__bf16)y[r];
    hv[r] = h;
    lv[r] = (__bf16)(y[r] - (float)h);
  }
  size_t tb = ((size_t)(row >> 7) * (DM / 64) + (tid >> 4)) * 16384;
  int off = (row & 127) * 128 + (((tid & 15) * 8) ^ ((row & 7) << 4));
  *(bf16x4*)(ph + tb + off) = hv;
  *(bf16x4*)(pl + tb + off) = lv;
}

// ---------------- Weight pack: fp32 [K][N] -> transposed swizzled hi/lo -----
__global__ __launch_bounds__(256) void packw_k(
    const float* __restrict__ W, char* __restrict__ dh, char* __restrict__ dl,
    int N, int qkv) {
  const int tn = blockIdx.x, tk = blockIdx.y, nkt = gridDim.y;
  __shared__ float L[64][132];
  const int k0 = tk * 64;
  const size_t srcbase = qkv ? ((size_t)tn * 131072 + (size_t)k0 * 128)
                             : ((size_t)k0 * N + (size_t)tn * 128);
  const int rstr = qkv ? 128 : N;
#pragma unroll
  for (int it = 0; it < 8; ++it) {
    int q = threadIdx.x + it * 256;
    int kk = q >> 5, c4 = (q & 31) * 4;
    float4 v = *(const float4*)(W + srcbase + (size_t)kk * rstr + c4);
    *(float4*)&L[kk][c4] = v;
  }
  __syncthreads();
  const size_t tb = ((size_t)tn * nkt + tk) * 16384;
#pragma unroll
  for (int it = 0; it < 4; ++it) {
    int o = threadIdx.x + it * 256;
    int n = o >> 3, k8 = o & 7;
    bf16x8 hv, lv;
#pragma unroll
    for (int j = 0; j < 8; ++j) {
      float x = L[k8 * 8 + j][n];
      __bf16 h = (__bf16)x;
      hv[j] = h;
      lv[j] = (__bf16)(x - (float)h);
    }
    int off = n * 128 + ((k8 * 16) ^ ((n & 7) << 4));
    *(bf16x8*)(dh + tb + off) = hv;
    *(bf16x8*)(dl + tb + off) = lv;
  }
}

// ---------------- V fp32 [b][h][s][d] -> V^T packed tiles (rows=d, k=s) -----
__global__ __launch_bounds__(256) void vtpack_k(
    const float* __restrict__ V, char* __restrict__ dh, char* __restrict__ dl) {
  const int st = blockIdx.x, bh = blockIdx.y;
  __shared__ float L[64][132];
  const float* src = V + ((size_t)bh * SS + st * 64) * HDD;
#pragma unroll
  for (int it = 0; it < 8; ++it) {
    int q = threadIdx.x + it * 256;
    int r = q >> 5, c4 = (q & 31) * 4;
    *(float4*)&L[r][c4] = *(const float4*)(src + (size_t)r * HDD + c4);
  }
  __syncthreads();
  const size_t tb = ((size_t)bh * 32 + st) * 16384;
#pragma unroll
  for (int it = 0; it < 4; ++it) {
    int o = threadIdx.x + it * 256;
    int d = o >> 3, s8 = o & 7;
    bf16x8 hv, lv;
#pragma unroll
    for (int j = 0; j < 8; ++j) {
      float x = L[s8 * 8 + j][d];
      __bf16 h = (__bf16)x;
      hv[j] = h;
      lv[j] = (__bf16)(x - (float)h);
    }
    int off = d * 128 + ((s8 * 16) ^ ((d & 7) << 4));
    *(bf16x8*)(dh + tb + off) = hv;
    *(bf16x8*)(dl + tb + off) = lv;
  }
}

// ---------------- old-style 2-barrier GEMM mainloop (NF=2 kernels) ----------
template <int NF>
__device__ __forceinline__ void gemm_main(
    const char* __restrict__ pAh, const char* __restrict__ pAl,
    const char* __restrict__ pBh, const char* __restrict__ pBl,
    size_t tA0, size_t tB0, int nkt, char* lds, f32x4 (&acc)[NF][4]) {
  const int tid = threadIdx.x, lane = tid & 63, w = tid >> 6;
  const int wm = w & 1, wn = w >> 1;
  const int swz = (lane & 7) << 4;
  const int l15 = lane & 15, l4 = lane >> 4;
  char* lAh = lds;
  char* lAl = lds + 16384;
  char* lBh = lds + 32768;
  char* lBl = lds + 32768 + NF * 4096;
  for (int t = 0; t < nkt; ++t) {
    const size_t oA = tA0 + (size_t)t * 16384;
    const size_t oB = tB0 + (size_t)t * 16384;
#pragma unroll
    for (int c = 0; c < 4; ++c) {
      const size_t go = (size_t)c * 4096 + w * 1024 + lane * 16;
      glds16(pAh + oA + go, lAh + c * 4096 + w * 1024);
      glds16(pAl + oA + go, lAl + c * 4096 + w * 1024);
    }
#pragma unroll
    for (int c = 0; c < NF; ++c) {
      const size_t go = (size_t)c * 4096 + w * 1024 + lane * 16;
      glds16(pBh + oB + go, lBh + c * 4096 + w * 1024);
      glds16(pBl + oB + go, lBl + c * 4096 + w * 1024);
    }
    __syncthreads();
#pragma unroll
    for (int ks = 0; ks < 2; ++ks) {
      const int kb = ks * 64 + l4 * 16;
      bf16x8 amh[4], aml[4], anh[NF], anl[NF];
#pragma unroll
      for (int f = 0; f < 4; ++f) {
        const int ra = (wm * 64 + f * 16 + l15) * 128 + (kb ^ swz);
        amh[f] = *(const bf16x8*)&lAh[ra];
        aml[f] = *(const bf16x8*)&lAl[ra];
      }
#pragma unroll
      for (int f = 0; f < NF; ++f) {
        const int rb = (wn * (NF * 16) + f * 16 + l15) * 128 + (kb ^ swz);
        anh[f] = *(const bf16x8*)&lBh[rb];
        anl[f] = *(const bf16x8*)&lBl[rb];
      }
#pragma unroll
      for (int nf = 0; nf < NF; ++nf)
#pragma unroll
        for (int mf = 0; mf < 4; ++mf) {
          acc[nf][mf] = __builtin_amdgcn_mfma_f32_16x16x32_bf16(
              anh[nf], amh[mf], acc[nf][mf], 0, 0, 0);
          acc[nf][mf] = __builtin_amdgcn_mfma_f32_16x16x32_bf16(
              anh[nf], aml[mf], acc[nf][mf], 0, 0, 0);
          acc[nf][mf] = __builtin_amdgcn_mfma_f32_16x16x32_bf16(
              anl[nf], amh[mf], acc[nf][mf], 0, 0, 0);
        }
    }
    __syncthreads();
  }
}

// ---------------- 8-wave deep-pipelined GEMM mainloop (T3+T4+T5) ------------
// 512 thr = 8 waves (2M x 4N), 128x128 tile, BK=64, double-buffered LDS
// (2 x 64 KiB), counted vmcnt(8): one stage (8 glds16/wave) stays in flight
// across barriers; never drain to 0 in the main loop.
__device__ __forceinline__ void gemm8_main(
    const char* __restrict__ pAh, const char* __restrict__ pAl,
    const char* __restrict__ pBh, const char* __restrict__ pBl,
    size_t tA0, size_t tB0, int nkt, char* lds, f32x4 (&acc)[2][4]) {
  const int tid = threadIdx.x, lane = tid & 63, wid = tid >> 6;
  const int wm = wid & 1, wn = wid >> 1;
  const int l15 = lane & 15, l4 = lane >> 4;

  auto stage = [&](int buf, int t) {
    const size_t oA = tA0 + (size_t)t * 16384;
    const size_t oB = tB0 + (size_t)t * 16384;
    char* lb = lds + buf * 65536;
#pragma unroll
    for (int c = 0; c < 2; ++c) {
      const size_t go = (size_t)c * 8192 + wid * 1024 + lane * 16;
      const int lo = c * 8192 + wid * 1024;
      glds16(pAh + oA + go, lb + lo);
      glds16(pAl + oA + go, lb + 16384 + lo);
      glds16(pBh + oB + go, lb + 32768 + lo);
      glds16(pBl + oB + go, lb + 49152 + lo);
    }
  };

  auto tile_comp = [&](int buf, bool pf, int pft) {
    char* lb = lds + buf * 65536;
    bf16x8 amh[2][4], aml[2][4], bnh[2][2], bnl[2][2];
#pragma unroll
    for (int ks = 0; ks < 2; ++ks) {
      const int kb = ks * 64 + l4 * 16;
#pragma unroll
      for (int mf = 0; mf < 4; ++mf) {
        const int rm = wm * 64 + mf * 16 + l15;
        const int ra = rm * 128 + (kb ^ ((rm & 7) << 4));
        amh[ks][mf] = *(const bf16x8*)(lb + ra);
        aml[ks][mf] = *(const bf16x8*)(lb + 16384 + ra);
      }
#pragma unroll
      for (int nf = 0; nf < 2; ++nf) {
        const int rn = wn * 32 + nf * 16 + l15;
        const int rb = rn * 128 + (kb ^ ((rn & 7) << 4));
        bnh[ks][nf] = *(const bf16x8*)(lb + 32768 + rb);
        bnl[ks][nf] = *(const bf16x8*)(lb + 49152 + rb);
      }
    }
    asm volatile("s_waitcnt lgkmcnt(0)" ::: "memory");  // own reads in regs
    asm volatile("s_barrier" ::: "memory");             // all waves done w/ buf
    if (pf) stage(buf, pft);                            // restage; hides under MFMA
    __builtin_amdgcn_s_setprio(1);
#pragma unroll
    for (int ks = 0; ks < 2; ++ks)
#pragma unroll
      for (int nf = 0; nf < 2; ++nf)
#pragma unroll
        for (int mf = 0; mf < 4; ++mf) {
          acc[nf][mf] = __builtin_amdgcn_mfma_f32_16x16x32_bf16(
              bnh[ks][nf], amh[ks][mf], acc[nf][mf], 0, 0, 0);
          acc[nf][mf] = __builtin_amdgcn_mfma_f32_16x16x32_bf16(
              bnh[ks][nf], aml[ks][mf], acc[nf][mf], 0, 0, 0);
          acc[nf][mf] = __builtin_amdgcn_mfma_f32_16x16x32_bf16(
              bnl[ks][nf], amh[ks][mf], acc[nf][mf], 0, 0, 0);
        }
    __builtin_amdgcn_s_setprio(0);
  };

  stage(0, 0);
  asm volatile("" ::: "memory");  // keep stage0/stage1 issue order (vmcnt FIFO)
  stage(1, 1);
  for (int t = 0; t < nkt - 1; ++t) {
    asm volatile("s_waitcnt vmcnt(8)" ::: "memory");  // tile t resident; t+1 in flight
    asm volatile("s_barrier" ::: "memory");
    tile_comp(t & 1, t + 2 < nkt, t + 2);
  }
  asm volatile("s_waitcnt vmcnt(0)" ::: "memory");    // last tile resident
  asm volatile("s_barrier" ::: "memory");
  tile_comp((nkt - 1) & 1, false, 0);
}

// ---------------- GEMM kernels (2-barrier path, NF=2) ------------------------
// MODE 2: + resid -> row-major (WO)    MODE 4: + bias + resid (FFN2)
template <int MODE, int NF>
__global__ __launch_bounds__(256, 3) void mgemm_k(
    const char* __restrict__ pAh, const char* __restrict__ pAl,
    const char* __restrict__ pBh, const char* __restrict__ pBl,
    float* __restrict__ C, const float* __restrict__ bias,
    const float* __restrict__ resid, int N, int K) {
  __shared__ char lds[32768 + NF * 8192];
  const int lane = threadIdx.x & 63, w = threadIdx.x >> 6;
  const int wm = w & 1, wn = w >> 1;
  const int l15 = lane & 15, l4 = lane >> 4;
  const int lin = blockIdx.y * gridDim.x + blockIdx.x;
  const int swzb = xcd_swz(lin, gridDim.x * gridDim.y);
  const int bx = swzb % gridDim.x, by = swzb / gridDim.x;
  const int nkt = K >> 6;
  const size_t tA0 = (size_t)by * nkt * 16384;
  const size_t tB0 = (size_t)(bx >> 1) * nkt * 16384 + (size_t)(bx & 1) * 8192;
  f32x4 acc[NF][4];
#pragma unroll
  for (int i = 0; i < NF; ++i)
#pragma unroll
    for (int j = 0; j < 4; ++j) acc[i][j] = (f32x4){0.f, 0.f, 0.f, 0.f};

  gemm_main<NF>(pAh, pAl, pBh, pBl, tA0, tB0, nkt, lds, acc);

  const int mBase = by * 128 + wm * 64 + l15;
  const int nBase = bx * (NF * 32) + wn * (NF * 16) + l4 * 4;
#pragma unroll
  for (int nf = 0; nf < NF; ++nf)
#pragma unroll
    for (int mf = 0; mf < 4; ++mf) {
      const int m = mBase + mf * 16;
      const int n = nBase + nf * 16;
      f32x4 v = acc[nf][mf];
      if (MODE == 2) {
        f32x4 rz = *(const f32x4*)(resid + (size_t)m * N + n);
        v += rz;
        *(f32x4*)(C + (size_t)m * N + n) = v;
      } else {  // MODE 4
        f32x4 bz = *(const f32x4*)(bias + n);
        f32x4 rz = *(const f32x4*)(resid + (size_t)m * N + n);
        v += bz + rz;
        *(f32x4*)(C + (size_t)m * N + n) = v;
      }
    }
}

// ---------------- Fused QKVG, 8-wave pipelined -------------------------------
// z=0: Q rotary->packed  z=1: K rotary->packed  z=2: V fp32 [b][h][s][d]
// z=3: silu -> gate row-major. Weights contiguous: offset z*2MB.
__global__ __launch_bounds__(512, 2) void qkvg8_k(
    const char* __restrict__ pXh, const char* __restrict__ pXl,
    const char* __restrict__ pWh, const char* __restrict__ pWl,
    float* __restrict__ V, float* __restrict__ G,
    char* __restrict__ pQh, char* __restrict__ pQl,
    char* __restrict__ pKh, char* __restrict__ pKl,
    const float* __restrict__ sq, const float* __restrict__ cq,
    const float* __restrict__ sk, const float* __restrict__ ck) {
  __shared__ char lds[131072];
  const int lane = threadIdx.x & 63, wid = threadIdx.x >> 6;
  const int wm = wid & 1, wn = wid >> 1;
  const int l15 = lane & 15, l4 = lane >> 4;
  const int lin = ((blockIdx.z * 32) + blockIdx.y) * 8 + blockIdx.x;
  const int swzb = xcd_swz(lin, 1024);
  const int bx = swzb & 7, by = (swzb >> 3) & 31, z = swzb >> 8;
  const int nkt = DM >> 6;  // 16
  const size_t tA0 = (size_t)by * nkt * 16384;
  const size_t tB0 = (size_t)bx * nkt * 16384;
  const size_t wo = (size_t)z << 21;  // z*2MB
  f32x4 acc[2][4];
#pragma unroll
  for (int i = 0; i < 2; ++i)
#pragma unroll
    for (int j = 0; j < 4; ++j) acc[i][j] = (f32x4){0.f, 0.f, 0.f, 0.f};

  gemm8_main(pXh, pXl, pWh + wo, pWl + wo, tA0, tB0, nkt, lds, acc);

  const int mBase = by * 128 + wm * 64 + l15;
  const int nBase = bx * 128 + wn * 32 + l4 * 4;
#pragma unroll
  for (int nf = 0; nf < 2; ++nf)
#pragma unroll
    for (int mf = 0; mf < 4; ++mf) {
      const int m = mBase + mf * 16;
      const int n = nBase + nf * 16;
      f32x4 v = acc[nf][mf];
      if (z == 2) {
        *(f32x4*)(V + (((size_t)(m >> 11) * HH + (n >> 7)) * SS + (m & (SS - 1)))
                          * HDD + (n & (HDD - 1))) = v;
      } else if (z == 3) {
#pragma unroll
        for (int r = 0; r < 4; ++r) v[r] = silu_f(v[r]);
        *(f32x4*)(G + (size_t)m * DM + n) = v;
      } else {  // rotary -> packed per-(b,h) tiles (rows=s, k=d)
        const float* tsn = (z == 0) ? sq : sk;
        const float* tcs = (z == 0) ? cq : ck;
        char* oh = (z == 0) ? pQh : pKh;
        char* ol = (z == 0) ? pQl : pKl;
        int s = m & (SS - 1);
        int d = n & (HDD - 1);
        f32x4 sn = *(const f32x4*)(tsn + (size_t)s * HDD + d);
        f32x4 cn = *(const f32x4*)(tcs + (size_t)s * HDD + d);
        float o0 = v[0] * cn[0] - v[1] * sn[0];
        float o1 = v[1] * cn[1] + v[0] * sn[1];
        float o2 = v[2] * cn[2] - v[3] * sn[2];
        float o3 = v[3] * cn[3] + v[2] * sn[3];
        float oo[4] = {o0, o1, o2, o3};
        bf16x4 hv, lv;
#pragma unroll
        for (int r = 0; r < 4; ++r) {
          __bf16 h = (__bf16)oo[r];
          hv[r] = h;
          lv[r] = (__bf16)(oo[r] - (float)h);
        }
        size_t tile = ((size_t)(m >> 11) * HH + (n >> 7)) * 32 + (s >> 7) * 2 + (d >> 6);
        size_t off = tile * 16384 + (s & 127) * 128 + (((d & 63) * 2) ^ ((s & 7) << 4));
        *(bf16x4*)(oh + off) = hv;
        *(bf16x4*)(ol + off) = lv;
      }
    }
}

// ---------------- FFN1, 8-wave pipelined: silu(+bias) -> packed -------------
__global__ __launch_bounds__(512, 2) void ffn1_8k(
    const char* __restrict__ pAh, const char* __restrict__ pAl,
    const char* __restrict__ pBh, const char* __restrict__ pBl,
    const float* __restrict__ bias, char* __restrict__ outH,
    char* __restrict__ outL) {
  __shared__ char lds[131072];
  const int lane = threadIdx.x & 63, wid = threadIdx.x >> 6;
  const int wm = wid & 1, wn = wid >> 1;
  const int l15 = lane & 15, l4 = lane >> 4;
  const int lin = blockIdx.y * gridDim.x + blockIdx.x;
  const int swzb = xcd_swz(lin, gridDim.x * gridDim.y);
  const int bx = swzb % gridDim.x, by = swzb / gridDim.x;
  const int nkt = DM >> 6;  // 16
  const size_t tA0 = (size_t)by * nkt * 16384;
  const size_t tB0 = (size_t)bx * nkt * 16384;
  const int N = FFN_;
  f32x4 acc[2][4];
#pragma unroll
  for (int i = 0; i < 2; ++i)
#pragma unroll
    for (int j = 0; j < 4; ++j) acc[i][j] = (f32x4){0.f, 0.f, 0.f, 0.f};

  gemm8_main(pAh, pAl, pBh, pBl, tA0, tB0, nkt, lds, acc);

  const int mBase = by * 128 + wm * 64 + l15;
  const int nBase = bx * 128 + wn * 32 + l4 * 4;
#pragma unroll
  for (int nf = 0; nf < 2; ++nf)
#pragma unroll
    for (int mf = 0; mf < 4; ++mf) {
      const int m = mBase + mf * 16;
      const int n = nBase + nf * 16;
      f32x4 v = acc[nf][mf];
      f32x4 bz = *(const f32x4*)(bias + n);
      bf16x4 hv, lv;
#pragma unroll
      for (int r = 0; r < 4; ++r) {
        float y = silu_f(v[r] + bz[r]);
        __bf16 h = (__bf16)y;
        hv[r] = h;
        lv[r] = (__bf16)(y - (float)h);
      }
      size_t tb = ((size_t)(m >> 7) * (N >> 6) + (n >> 6)) * 16384;
      int off = (m & 127) * 128 + (((n & 63) * 2) ^ ((m & 7) << 4));
      *(bf16x4*)(outH + tb + off) = hv;
      *(bf16x4*)(outL + tb + off) = lv;
    }
}

// ---------------- Retention via split-bf16 MFMA (unchanged) ------------------
__global__ __launch_bounds__(256, 2) void mattn_k(
    const char* __restrict__ pQh, const char* __restrict__ pQl,
    const char* __restrict__ pKh, const char* __restrict__ pKl,
    const char* __restrict__ pVh, const char* __restrict__ pVl,
    const float* __restrict__ lg2g, float* __restrict__ Y) {
  __shared__ char Kls[2][2][8192];
  __shared__ char Vls[2][16384];
  __shared__ char Pls[2][8192];
  const int lin = blockIdx.y * 32 + blockIdx.x;
  const int swzb = xcd_swz(lin, 512);
  const int qt = 31 - (swzb & 31);
  const int bh = swzb >> 5;
  const int tid = threadIdx.x, lane = tid & 63, w = tid >> 6;
  const int wn = w & 1, wq = w >> 1;
  const int l15 = lane & 15, lg = lane >> 4;
  const float lg2 = lg2g[bh & 7];
  const size_t tb0 = (size_t)bh * 32;
  const int n0 = qt * 64;
  const int nt = qt + 1;

  bf16x8 qh[2][4], ql[2][4];
#pragma unroll
  for (int nf = 0; nf < 2; ++nf) {
    int rr = n0 + wn * 32 + nf * 16 + l15;
    size_t rowbase = (tb0 + (size_t)(rr >> 7) * 2) * 16384 + (size_t)(rr & 127) * 128;
    int sw = (rr & 7) << 4;
#pragma unroll
    for (int ks = 0; ks < 4; ++ks) {
      int d = ks * 32 + lg * 8;
      size_t a = rowbase + (size_t)(d >> 6) * 16384 + (((d & 63) * 2) ^ sw);
      qh[nf][ks] = *(const bf16x8*)(pQh + a);
      ql[nf][ks] = *(const bf16x8*)(pQl + a);
    }
  }

  f32x4 yacc[2][4];
#pragma unroll
  for (int i = 0; i < 2; ++i)
#pragma unroll
    for (int j = 0; j < 4; ++j) yacc[i][j] = (f32x4){0.f, 0.f, 0.f, 0.f};

  auto stageK = [&](int mt) {
    size_t half = (size_t)(mt & 1) * 8192;
#pragma unroll
    for (int dt = 0; dt < 2; ++dt) {
      size_t tile = (tb0 + (size_t)(mt >> 1) * 2 + dt) * 16384 + half;
#pragma unroll
      for (int c = 0; c < 2; ++c) {
        size_t go = (size_t)c * 4096 + w * 1024 + lane * 16;
        glds16(pKh + tile + go, &Kls[dt][0][c * 4096 + w * 1024]);
        glds16(pKl + tile + go, &Kls[dt][1][c * 4096 + w * 1024]);
      }
    }
  };
  auto stageV = [&](int mt) {
    size_t tile = (tb0 + mt) * 16384;
#pragma unroll
    for (int c = 0; c < 4; ++c) {
      size_t go = (size_t)c * 4096 + w * 1024 + lane * 16;
      glds16(pVh + tile + go, &Vls[0][c * 4096 + w * 1024]);
      glds16(pVl + tile + go, &Vls[1][c * 4096 + w * 1024]);
    }
  };

  stageK(0);
  stageV(0);
  __syncthreads();

  for (int mt = 0; mt < nt; ++mt) {
    f32x4 sacc[2][2];
#pragma unroll
    for (int i = 0; i < 2; ++i)
#pragma unroll
      for (int j = 0; j < 2; ++j) sacc[i][j] = (f32x4){0.f, 0.f, 0.f, 0.f};
#pragma unroll
    for (int ks = 0; ks < 4; ++ks) {
      int d = ks * 32 + lg * 8;
      bf16x8 kh[2], kl[2];
#pragma unroll
      for (int mf = 0; mf < 2; ++mf) {
        int m = wq * 32 + mf * 16 + l15;
        int off = (m & 63) * 128 + (((d & 63) * 2) ^ ((m & 7) << 4));
        kh[mf] = *(const bf16x8*)&Kls[d >> 6][0][off];
        kl[mf] = *(const bf16x8*)&Kls[d >> 6][1][off];
      }
#pragma unroll
      for (int nf = 0; nf < 2; ++nf)
#pragma unroll
        for (int mf = 0; mf < 2; ++mf) {
          sacc[nf][mf] = __builtin_amdgcn_mfma_f32_16x16x32_bf16(
              qh[nf][ks], kh[mf], sacc[nf][mf], 0, 0, 0);
          sacc[nf][mf] = __builtin_amdgcn_mfma_f32_16x16x32_bf16(
              qh[nf][ks], kl[mf], sacc[nf][mf], 0, 0, 0);
          sacc[nf][mf] = __builtin_amdgcn_mfma_f32_16x16x32_bf16(
              ql[nf][ks], kh[mf], sacc[nf][mf], 0, 0, 0);
        }
    }
    asm volatile("s_barrier" ::: "memory");
    if (mt + 1 < nt) stageK(mt + 1);

#pragma unroll
    for (int nf = 0; nf < 2; ++nf)
#pragma unroll
      for (int mf = 0; mf < 2; ++mf)
#pragma unroll
        for (int r = 0; r < 4; ++r) {
          int nl = wn * 32 + nf * 16 + lg * 4 + r;
          int ml = wq * 32 + mf * 16 + l15;
          int diff = (n0 + nl) - (mt * 64 + ml);
          float dec = (diff >= 0) ? exp2f((float)diff * lg2) : 0.0f;
          float p = sacc[nf][mf][r] * dec;
          __bf16 h = (__bf16)p;
          int off = nl * 128 + ((ml * 2) ^ ((nl & 7) << 4));
          *(__bf16*)&Pls[0][off] = h;
          *(__bf16*)&Pls[1][off] = (__bf16)(p - (float)h);
        }
    asm volatile("s_waitcnt lgkmcnt(0)" ::: "memory");
    asm volatile("s_barrier" ::: "memory");

#pragma unroll
    for (int ks = 0; ks < 2; ++ks) {
      int mchunk = ks * 32 + lg * 8;
      bf16x8 ph[2], pl2[2], vh[4], vl2[4];
#pragma unroll
      for (int nf = 0; nf < 2; ++nf) {
        int nl = wn * 32 + nf * 16 + l15;
        int off = nl * 128 + ((mchunk * 2) ^ ((nl & 7) << 4));
        ph[nf]  = *(const bf16x8*)&Pls[0][off];
        pl2[nf] = *(const bf16x8*)&Pls[1][off];
      }
#pragma unroll
      for (int df = 0; df < 4; ++df) {
        int d = wq * 64 + df * 16 + l15;
        int off = d * 128 + ((mchunk * 2) ^ ((d & 7) << 4));
        vh[df]  = *(const bf16x8*)&Vls[0][off];
        vl2[df] = *(const bf16x8*)&Vls[1][off];
      }
#pragma unroll
      for (int nf = 0; nf < 2; ++nf)
#pragma unroll
        for (int df = 0; df < 4; ++df) {
          yacc[nf][df] = __builtin_amdgcn_mfma_f32_16x16x32_bf16(
              ph[nf], vh[df], yacc[nf][df], 0, 0, 0);
          yacc[nf][df] = __builtin_amdgcn_mfma_f32_16x16x32_bf16(
              ph[nf], vl2[df], yacc[nf][df], 0, 0, 0);
          yacc[nf][df] = __builtin_amdgcn_mfma_f32_16x16x32_bf16(
              pl2[nf], vh[df], yacc[nf][df], 0, 0, 0);
        }
    }
    asm volatile("s_barrier" ::: "memory");
    if (mt + 1 < nt) stageV(mt + 1);
    __syncthreads();
  }

  const size_t yrow0 = (size_t)(bh >> 3) * SS + n0;
  const int hcol = (bh & 7) * HDD;
#pragma unroll
  for (int nf = 0; nf < 2; ++nf)
#pragma unroll
    for (int df = 0; df < 4; ++df)
#pragma unroll
      for (int r = 0; r < 4; ++r) {
        int nl = wn * 32 + nf * 16 + lg * 4 + r;
        int d  = wq * 64 + df * 16 + l15;
        Y[(yrow0 + nl) * DM + hcol + d] = yacc[nf][df][r];
      }
}

// ---------------- GroupNorm * gate -> packed hi/lo swizzled A-operand -------
__global__ __launch_bounds__(256) void gn_gate_k(
    const float* __restrict__ Y, const float* __restrict__ w,
    const float* __restrict__ b, const float* __restrict__ G,
    char* __restrict__ ph, char* __restrict__ pl) {
  int g    = blockIdx.x * 4 + (threadIdx.x >> 6);
  int lane = threadIdx.x & 63;
  float2 v = *(const float2*)(Y + (size_t)g * HDD + lane * 2);
  float s = v.x + v.y, q = v.x * v.x + v.y * v.y;
#pragma unroll
  for (int o = 32; o > 0; o >>= 1) { s += __shfl_xor(s, o); q += __shfl_xor(q, o); }
  float mu  = s * (1.0f / HDD);
  float var = q * (1.0f / HDD) - mu * mu;
  float rs  = 1.0f / sqrtf(var + 1e-5f);
  int m   = g >> 3;
  int col = (g & 7) * HDD + lane * 2;
  float2 wv = *(const float2*)(w + col);
  float2 bv = *(const float2*)(b + col);
  float2 gv = *(const float2*)(G + (size_t)g * HDD + lane * 2);
  float ox = ((v.x - mu) * rs * wv.x + bv.x) * gv.x;
  float oy = ((v.y - mu) * rs * wv.y + bv.y) * gv.y;
  __bf16 hx = (__bf16)ox, hy = (__bf16)oy;
  bf16x2 hv, lv;
  hv[0] = hx; hv[1] = hy;
  lv[0] = (__bf16)(ox - (float)hx); lv[1] = (__bf16)(oy - (float)hy);
  size_t tb = ((size_t)(m >> 7) * (DM / 64) + (col >> 6)) * 16384;
  int off = (m & 127) * 128 + (((col & 63) * 2) ^ ((m & 7) << 4));
  *(bf16x2*)(ph + tb + off) = hv;
  *(bf16x2*)(pl + tb + off) = lv;
}

// ---------------- driver -----------------------------------------------------
extern "C" void kernel_launch(void* const* d_in, const int* in_sizes, int n_in,
                              void* d_out, int out_size, void* d_ws, size_t ws_size,
                              hipStream_t stream) {
  (void)in_sizes; (void)n_in; (void)out_size; (void)ws_size;
  const float* X0   = (const float*)d_in[0];
  const float* ln1w = (const float*)d_in[1];
  const float* ln1b = (const float*)d_in[2];
  const float* ln2w = (const float*)d_in[3];
  const float* ln2b = (const float*)d_in[4];
  const float* WQ   = (const float*)d_in[5];
  const float* WK   = (const float*)d_in[6];
  const float* WV   = (const float*)d_in[7];
  const float* gnw  = (const float*)d_in[8];
  const float* gnb  = (const float*)d_in[9];
  const float* WG   = (const float*)d_in[10];
  const float* WO   = (const float*)d_in[11];
  const float* W1   = (const float*)d_in[12];
  const float* B1   = (const float*)d_in[13];
  const float* W2   = (const float*)d_in[14];
  const float* B2   = (const float*)d_in[15];

  char* wsb = (char*)d_ws;
  const size_t MB = 1 << 20;
  float* bufA = (float*)(wsb + 0 * MB);    // X carry
  float* bufB = (float*)(wsb + 16 * MB);   // Y (WO out / FFN resid)
  float* bufE = (float*)(wsb + 32 * MB);   // V fp32
  float* bufF = (float*)(wsb + 48 * MB);   // gate
  float* bufG = (float*)(wsb + 64 * MB);   // Yh
  float* sq   = (float*)(wsb + 80 * MB);
  float* cq   = (float*)(wsb + 81 * MB);
  float* sk   = (float*)(wsb + 82 * MB);
  float* ck   = (float*)(wsb + 83 * MB);
  float* lg2g = (float*)(wsb + 84 * MB);
  char* pXh = wsb + 85 * MB;
  char* pXl = wsb + 93 * MB;
  char* pWh = wsb + 101 * MB;   // 26 MB (Q,K,V,G,O contiguous 2MB each; W1 8MB; W2 8MB)
  char* pWl = wsb + 127 * MB;   // 26 MB
  char* R   = wsb + 153 * MB;   // overlap region: attn phase vs FFN phase
  char* pFh = R;                // 32 MB (FFN)
  char* pFl = R + 32 * MB;
  char* pQh = R;                // 8 MB (attention)
  char* pQl = R + 8 * MB;
  char* pKh = R + 16 * MB;
  char* pKl = R + 24 * MB;
  char* pVh = R + 32 * MB;
  char* pVl = R + 40 * MB;
  const size_t oWQ = 0, oW1 = (size_t)10 << 20, oWO = (size_t)8 << 20,
               oW2 = (size_t)18 << 20;

  init_tables_k<<<SS, HDD, 0, stream>>>(sq, cq, sk, ck, lg2g);

  for (int i = 0; i < LN_; ++i) {
    const float* Xin = (i == 0) ? X0 : bufA;
    // pack layer weights: Q,K,V,G consecutive (2MB each), then O, W1, W2
    packw_k<<<dim3(8, 16), 256, 0, stream>>>(WQ + (size_t)i * 1048576, pWh + oWQ, pWl + oWQ, 1024, 1);
    packw_k<<<dim3(8, 16), 256, 0, stream>>>(WK + (size_t)i * 1048576, pWh + 2 * MB, pWl + 2 * MB, 1024, 1);
    packw_k<<<dim3(8, 16), 256, 0, stream>>>(WV + (size_t)i * 1048576, pWh + 4 * MB, pWl + 4 * MB, 1024, 1);
    packw_k<<<dim3(8, 16), 256, 0, stream>>>(WG + (size_t)i * 1048576, pWh + 6 * MB, pWl + 6 * MB, 1024, 0);
    packw_k<<<dim3(8, 16), 256, 0, stream>>>(WO + (size_t)i * 1048576, pWh + oWO, pWl + oWO, 1024, 0);
    packw_k<<<dim3(32, 16), 256, 0, stream>>>(W1 + (size_t)i * 4194304, pWh + oW1, pWl + oW1, 4096, 0);
    packw_k<<<dim3(8, 64), 256, 0, stream>>>(W2 + (size_t)i * 4194304, pWh + oW2, pWl + oW2, 1024, 0);

    ln_pack_k<<<RR, 256, 0, stream>>>(Xin, ln1w + i * DM, ln1b + i * DM, pXh, pXl);
    qkvg8_k<<<dim3(8, 32, 4), 512, 0, stream>>>(pXh, pXl, pWh, pWl, bufE, bufF,
                                                pQh, pQl, pKh, pKl, sq, cq, sk, ck);
    vtpack_k<<<dim3(32, 16), 256, 0, stream>>>(bufE, pVh, pVl);
    mattn_k<<<dim3(32, 16), 256, 0, stream>>>(pQh, pQl, pKh, pKl, pVh, pVl, lg2g, bufG);
    gn_gate_k<<<RR * HH / 4, 256, 0, stream>>>(bufG, gnw + i * DM, gnb + i * DM,
                                               bufF, pXh, pXl);
    mgemm_k<2, 2><<<dim3(16, 32), 256, 0, stream>>>(pXh, pXl, pWh + oWO, pWl + oWO,
                                                    bufB, nullptr, Xin, DM, DM);
    ln_pack_k<<<RR, 256, 0, stream>>>(bufB, ln2w + i * DM, ln2b + i * DM, pXh, pXl);
    ffn1_8k<<<dim3(32, 32), 512, 0, stream>>>(pXh, pXl, pWh + oW1, pWl + oW1,
                                              B1 + (size_t)i * FFN_, pFh, pFl);
    float* Xout = (i == LN_ - 1) ? (float*)d_out : bufA;
    mgemm_k<4, 2><<<dim3(16, 32), 256, 0, stream>>>(pFh, pFl, pWh + oW2, pWl + oW2,
                                                    Xout, B2 + (size_t)i * DM, bufB,
                                                    DM, FFN_);
  }
}